// Round 4
// baseline (296.829 us; speedup 1.0000x reference)
//
#include <hip/hip_runtime.h>
#include <hip/hip_bf16.h>
#include <stdint.h>
#include <string.h>

// B=2, S=2048, D_MODEL=1024, H=16, Dh=64
#define SEQ   2048
#define DM    1024
#define NH    16
#define NB    2

typedef __attribute__((ext_vector_type(8))) short bf16x8;
typedef __attribute__((ext_vector_type(4))) float f32x4;
typedef unsigned short u16;
typedef unsigned int   u32;

__device__ __forceinline__ u16 f2bf(float f) {
    u32 u = __float_as_uint(f);
    u += 0x7FFF + ((u >> 16) & 1);   // RNE
    return (u16)(u >> 16);
}
__device__ __forceinline__ u32 pk2bf(float a, float b) {
    __hip_bfloat162 p = __float22bfloat162_rn(make_float2(a, b));
    u32 u; memcpy(&u, &p, 4); return u;
}
__device__ __forceinline__ float fexp2(float x) {
#if __has_builtin(__builtin_amdgcn_exp2f)
    return __builtin_amdgcn_exp2f(x);
#else
    return exp2f(x);
#endif
}
// async global->LDS, 16B/lane; LDS dest = wave-uniform base + lane*16
__device__ __forceinline__ void gl_lds16(const void* g, void* l) {
    __builtin_amdgcn_global_load_lds(
        (const __attribute__((address_space(1))) u32*)g,
        (__attribute__((address_space(3))) u32*)l, 16, 0, 0);
}

// ---------------------------------------------------------------------------
// fp32 -> bf16 bulk convert; Wq pre-scaled by 0.125*log2(e) (exp2 domain).
// ---------------------------------------------------------------------------
struct CvtArgs {
    const float* s[7];
    u16* d[7];
    float scale[7];
    int start[8];
};
__global__ __launch_bounds__(256) void cvt_kernel(CvtArgs a) {
    int bid = blockIdx.x;
    int seg = 0;
#pragma unroll
    for (int i = 1; i < 7; ++i) if (bid >= a.start[i]) seg = i;
    float sc = a.scale[seg];
    size_t base = (size_t)(bid - a.start[seg]) * 2048 + threadIdx.x * 8;
    const float4* s4 = (const float4*)(a.s[seg] + base);
    float4 x = s4[0], y = s4[1];
    u32 r[4];
    r[0] = pk2bf(x.x*sc, x.y*sc); r[1] = pk2bf(x.z*sc, x.w*sc);
    r[2] = pk2bf(y.x*sc, y.y*sc); r[3] = pk2bf(y.z*sc, y.w*sc);
    *(uint4*)(a.d[seg] + base) = *(uint4*)r;
}

// ---------------------------------------------------------------------------
// mask -> bits; word = bits[(b*2048+m)*64 + n/32]
// ---------------------------------------------------------------------------
__global__ void maskpack_kernel(const int* __restrict__ mask,
                                unsigned int* __restrict__ bits) {
    int gid = blockIdx.x * 256 + threadIdx.x;
    int m = mask[gid];
    unsigned long long bal = __ballot(m != 0);
    int lane = threadIdx.x & 63;
    if (lane == 0)       bits[gid >> 5] = (u32)(bal & 0xFFFFFFFFull);
    else if (lane == 32) bits[gid >> 5] = (u32)(bal >> 32);
}

// ---------------------------------------------------------------------------
// bf16 GEMM, BK=32, double-buffered LDS, ONE barrier per k-iter with
// global_load_lds prefetch issued right after the barrier (full iter to land).
// XOR swizzle: LDS chunk c holds global chunk c ^ ((row>>1)&3)  (4 chunks/row).
// RT=4: 128x128 tile; RT=2: 64x128 tile. 256 threads, waves 2x2.
// mode 0: bf16 (B,H,S,64); mode 1: bf16 (B,H,64,S); mode 2: fp32 row-major.
// ---------------------------------------------------------------------------
template<int RT>
__device__ __forceinline__ void gemm_body(const u16* __restrict__ A,
                                          const u16* __restrict__ Bm,
                                          void* __restrict__ Y,
                                          int rtile, int ctile, int mode,
                                          u16* sA, u16* sB) {
    constexpr int ABUF = RT * 32 * 32;          // u16 per A buffer
    constexpr int BBUF = 128 * 32;
    const int tid  = threadIdx.x;
    const int wv   = tid >> 6, lane = tid & 63;
    const int quad = lane >> 4, ln = lane & 15;
    const int wr   = wv >> 1,  wc  = wv & 1;

    const int lr4 = lane >> 2;                          // row in 16-row shot
    const int lcc = ((lane & 3) ^ ((lane >> 3) & 3)) * 8;  // swizzled src col

    const u16* gA[RT/2]; u16* lA[RT/2];
#pragma unroll
    for (int s = 0; s < RT/2; ++s) {
        int seg = wv * (RT/2) + s;
        gA[s] = A + (size_t)(rtile * (RT*32) + seg*16 + lr4) * 1024 + lcc;
        lA[s] = sA + seg * 512;
    }
    const u16* gB[2]; u16* lB[2];
#pragma unroll
    for (int s = 0; s < 2; ++s) {
        int seg = wv * 2 + s;
        gB[s] = Bm + (size_t)(ctile * 128 + seg*16 + lr4) * 1024 + lcc;
        lB[s] = sB + seg * 512;
    }

    f32x4 acc[RT][4];
#pragma unroll
    for (int i = 0; i < RT; ++i)
#pragma unroll
        for (int j = 0; j < 4; ++j) acc[i][j] = (f32x4){0.f,0.f,0.f,0.f};

    const int c0 = (quad ^ ((ln >> 1) & 3)) * 8;

    // prologue: stage kt=0 into buf 0
#pragma unroll
    for (int s = 0; s < RT/2; ++s) gl_lds16(gA[s], lA[s]);
#pragma unroll
    for (int s = 0; s < 2; ++s)    gl_lds16(gB[s], lB[s]);

    for (int kt = 0; kt < 32; ++kt) {
        __syncthreads();                 // drains own vmcnt: buf[kt&1] visible
        if (kt < 31) {                   // prefetch kt+1 into other buffer
            int nb = (kt + 1) & 1;
#pragma unroll
            for (int s = 0; s < RT/2; ++s)
                gl_lds16(gA[s] + (kt+1)*32, lA[s] + nb*ABUF);
#pragma unroll
            for (int s = 0; s < 2; ++s)
                gl_lds16(gB[s] + (kt+1)*32, lB[s] + nb*BBUF);
        }
        const u16* sAb = sA + (kt & 1) * ABUF;
        const u16* sBb = sB + (kt & 1) * BBUF;
        bf16x8 af[RT], bfr[4];
#pragma unroll
        for (int rt = 0; rt < RT; ++rt)
            af[rt] = *(const bf16x8*)(sAb + (wr*(RT*16) + rt*16 + ln) * 32 + c0);
#pragma unroll
        for (int ct = 0; ct < 4; ++ct)
            bfr[ct] = *(const bf16x8*)(sBb + (wc*64 + ct*16 + ln) * 32 + c0);
#pragma unroll
        for (int rt = 0; rt < RT; ++rt)
#pragma unroll
            for (int ct = 0; ct < 4; ++ct)
                acc[rt][ct] = __builtin_amdgcn_mfma_f32_16x16x32_bf16(
                    af[rt], bfr[ct], acc[rt][ct], 0, 0, 0);
    }

#pragma unroll
    for (int rt = 0; rt < RT; ++rt) {
#pragma unroll
        for (int ct = 0; ct < 4; ++ct) {
#pragma unroll
            for (int i = 0; i < 4; ++i) {
                int R = rtile*(RT*32) + wr*(RT*16) + rt*16 + quad*4 + i;
                int C = ctile*128 + wc*64 + ct*16 + ln;
                float val = acc[rt][ct][i];
                if (mode == 0) {
                    int b = R >> 11, s = R & 2047, h = C >> 6, d = C & 63;
                    ((u16*)Y)[((size_t)((b*NH + h) * SEQ + s) << 6) + d] = f2bf(val);
                } else if (mode == 1) {
                    int h = R >> 6, d = R & 63, b = C >> 11, n = C & 2047;
                    ((u16*)Y)[((size_t)((b*NH + h) * 64 + d) << 11) + n] = f2bf(val);
                } else {
                    ((float*)Y)[(size_t)R * 1024 + C] = val;
                }
            }
        }
    }
}

struct QKVArgs { const u16* A[3]; const u16* B[3]; u16* Y[3]; };

__global__ __launch_bounds__(256) void gemm_qkv(QKVArgs g) {
    __shared__ u16 sA[2 * 128 * 32];
    __shared__ u16 sB[2 * 128 * 32];
    int z = blockIdx.z;
    if (z == 2)
        gemm_body<4>(g.A[2], g.B[2], g.Y[2], blockIdx.y, blockIdx.x, 1, sA, sB);
    else
        gemm_body<4>(g.A[z], g.B[z], g.Y[z], blockIdx.x, blockIdx.y, 0, sA, sB);
}

__global__ __launch_bounds__(256) void gemm_out(const u16* __restrict__ A,
                                                const u16* __restrict__ Bm,
                                                float* __restrict__ Y) {
    __shared__ u16 sA[2 * 64 * 32];
    __shared__ u16 sB[2 * 128 * 32];
    gemm_body<2>(A, Bm, Y, blockIdx.x, blockIdx.y, 2, sA, sB);
}

// ---------------------------------------------------------------------------
// Flash attention v2: 128 m-rows per block (wave owns 32 rows = 2 m-subtiles),
// K/V double-buffered with 1-barrier prefetch pipeline, wave-private P (no
// P barrier), mask words prefetched 1 iter ahead. Q pre-scaled (exp2 domain).
// ---------------------------------------------------------------------------
__global__ __launch_bounds__(256) void attn_kernel(
    const u16* __restrict__ qw,
    const u16* __restrict__ kw,
    const u16* __restrict__ vt,
    const u32* __restrict__ mbits,
    u16* __restrict__ ctx) {

    constexpr int PST = 68;                 // P row stride (34 dw == 2 mod 32)
    __shared__ u16 sK[2 * 64 * 64];
    __shared__ u16 sV[2 * 64 * 64];
    __shared__ u16 sP[4 * 32 * PST];

    const int mtile = blockIdx.x;           // 0..15 (128 rows each)
    const int bh    = blockIdx.y;           // 0..31
    const int b     = bh >> 4;
    const int tid   = threadIdx.x;
    const int wv    = tid >> 6, lane = tid & 63;
    const int quad  = lane >> 4, ln = lane & 15;
    const int m0    = mtile * 128;

    const size_t hbase = (size_t)bh * SEQ * 64;

    // Q fragments: wave wv owns m-subtiles (wv*2+mt), mt=0,1
    bf16x8 qf[2][2];
#pragma unroll
    for (int mt = 0; mt < 2; ++mt) {
        const u16* qp = qw + hbase + (size_t)(m0 + (wv*2+mt)*16 + ln) * 64 + quad*8;
        qf[mt][0] = *(const bf16x8*)(qp);
        qf[mt][1] = *(const bf16x8*)(qp + 32);
    }

    f32x4 o[2][4], lsum[2];
#pragma unroll
    for (int mt = 0; mt < 2; ++mt) {
        lsum[mt] = (f32x4){0.f,0.f,0.f,0.f};
#pragma unroll
        for (int j = 0; j < 4; ++j) o[mt][j] = (f32x4){0.f,0.f,0.f,0.f};
    }

    bf16x8 ones;
#pragma unroll
    for (int i = 0; i < 8; ++i) ones[i] = (short)0x3F80;   // bf16 1.0

    const u32* mbase = mbits + (size_t)(b * SEQ + m0 + wv*32 + quad*4) * 64;
    const u32 mlo = 1u << ln;
    const u32 mhi = 1u << (ln + 16);

    // staging: 2 shots each for K and V; seg = s*4+wv; swizzled source chunk
    const int lr = lane >> 3;
    const int lc = (lane & 7) ^ lr;
    const u16* gK[2]; const u16* gV[2];
    u16 *lK[2], *lV[2];
#pragma unroll
    for (int s = 0; s < 2; ++s) {
        int seg = s * 4 + wv;
        gK[s] = kw + hbase + (size_t)(seg*8 + lr) * 64 + lc*8;
        gV[s] = vt + hbase + (size_t)(seg*8 + lr) * SEQ + lc*8;
        lK[s] = sK + seg * 512;
        lV[s] = sV + seg * 512;
    }

    const int c0 = (quad ^ (ln & 7)) * 8;
    u16* sPw = sP + wv * 32 * PST;

    // prologue: stage tile 0 into buf 0; prefetch mask words for nt=0
#pragma unroll
    for (int s = 0; s < 2; ++s) { gl_lds16(gK[s], lK[s]); gl_lds16(gV[s], lV[s]); }
    uint2 wwA[2][4];
#pragma unroll
    for (int mt = 0; mt < 2; ++mt)
#pragma unroll
        for (int i = 0; i < 4; ++i)
            wwA[mt][i] = *(const uint2*)(mbase + (mt*16 + i)*64);

    for (int nt = 0; nt < SEQ / 64; ++nt) {
        __syncthreads();                 // buf[nt&1] visible; prev reads done
        uint2 wwB[2][4];
        if (nt < SEQ/64 - 1) {           // prefetch nt+1 (K/V + mask)
            int nb = (nt + 1) & 1;
#pragma unroll
            for (int s = 0; s < 2; ++s) {
                gl_lds16(gK[s] + (size_t)(nt+1) * 4096, lK[s] + nb*4096);
                gl_lds16(gV[s] + (nt+1) * 64,           lV[s] + nb*4096);
            }
#pragma unroll
            for (int mt = 0; mt < 2; ++mt)
#pragma unroll
                for (int i = 0; i < 4; ++i)
                    wwB[mt][i] = *(const uint2*)(mbase + (mt*16 + i)*64 + (nt+1)*2);
        }
        const u16* sKb = sK + (nt & 1) * 4096;
        const u16* sVb = sV + (nt & 1) * 4096;

        // S = Q K^T (exp2 domain); K frags shared across both m-subtiles
        f32x4 s4[2][4];
#pragma unroll
        for (int ct = 0; ct < 4; ++ct) {
            const u16* kp = sKb + (ct*16 + ln) * 64;
            bf16x8 k0 = *(const bf16x8*)(kp + c0);
            bf16x8 k1 = *(const bf16x8*)(kp + (c0 ^ 32));
#pragma unroll
            for (int mt = 0; mt < 2; ++mt) {
                f32x4 z = (f32x4){0.f, 0.f, 0.f, 0.f};
                z = __builtin_amdgcn_mfma_f32_16x16x32_bf16(qf[mt][0], k0, z, 0, 0, 0);
                z = __builtin_amdgcn_mfma_f32_16x16x32_bf16(qf[mt][1], k1, z, 0, 0, 0);
                s4[mt][ct] = z;
            }
        }

        // p = exp2(masked ? -1e9 : s); write P into wave-private LDS region
#pragma unroll
        for (int mt = 0; mt < 2; ++mt) {
#pragma unroll
            for (int ct = 0; ct < 4; ++ct) {
                const u32 mb = (ct & 1) ? mhi : mlo;
#pragma unroll
                for (int ii = 0; ii < 4; ii += 2) {
                    u32 w0 = (ct & 2) ? wwA[mt][ii].y   : wwA[mt][ii].x;
                    u32 w1 = (ct & 2) ? wwA[mt][ii+1].y : wwA[mt][ii+1].x;
                    float p0 = fexp2((w0 & mb) ? -1e9f : s4[mt][ct][ii]);
                    float p1 = fexp2((w1 & mb) ? -1e9f : s4[mt][ct][ii+1]);
                    u32 u = pk2bf(p0, p1);
                    int row = mt*16 + quad*4 + ii;
                    sPw[ row    * PST + ct*16 + ln] = (u16)u;
                    sPw[(row+1) * PST + ct*16 + ln] = (u16)(u >> 16);
                }
            }
        }
        // NO barrier: P region is wave-private; in-wave ds ordering suffices.

        // O += P V ; lsum += P * ones
        bf16x8 pf[2][2];
#pragma unroll
        for (int mt = 0; mt < 2; ++mt) {
            const u16* pp = sPw + (mt*16 + ln) * PST;
            pf[mt][0] = *(const bf16x8*)(pp + quad*8);
            pf[mt][1] = *(const bf16x8*)(pp + 32 + quad*8);
            lsum[mt] = __builtin_amdgcn_mfma_f32_16x16x32_bf16(pf[mt][0], ones, lsum[mt], 0, 0, 0);
            lsum[mt] = __builtin_amdgcn_mfma_f32_16x16x32_bf16(pf[mt][1], ones, lsum[mt], 0, 0, 0);
        }
#pragma unroll
        for (int ct = 0; ct < 4; ++ct) {
            const u16* vp = sVb + (ct*16 + ln) * 64;
            bf16x8 v0 = *(const bf16x8*)(vp + c0);
            bf16x8 v1 = *(const bf16x8*)(vp + (c0 ^ 32));
#pragma unroll
            for (int mt = 0; mt < 2; ++mt) {
                o[mt][ct] = __builtin_amdgcn_mfma_f32_16x16x32_bf16(pf[mt][0], v0, o[mt][ct], 0, 0, 0);
                o[mt][ct] = __builtin_amdgcn_mfma_f32_16x16x32_bf16(pf[mt][1], v1, o[mt][ct], 0, 0, 0);
            }
        }

        // rotate mask prefetch
#pragma unroll
        for (int mt = 0; mt < 2; ++mt)
#pragma unroll
            for (int i = 0; i < 4; ++i)
                wwA[mt][i] = wwB[mt][i];
    }

#pragma unroll
    for (int mt = 0; mt < 2; ++mt)
#pragma unroll
        for (int i = 0; i < 4; ++i) {
            float inv = 1.f / lsum[mt][i];
            int m = m0 + (wv*2+mt)*16 + quad*4 + i;
            size_t base = ((size_t)(b * SEQ + m) << 10) + (bh & 15) * 64;
#pragma unroll
            for (int ct = 0; ct < 4; ++ct)
                ctx[base + ct*16 + ln] = f2bf(o[mt][ct][i] * inv);
        }
}

// ---------------------------------------------------------------------------
extern "C" void kernel_launch(void* const* d_in, const int* in_sizes, int n_in,
                              void* d_out, int out_size, void* d_ws, size_t ws_size,
                              hipStream_t stream) {
    const float* q    = (const float*)d_in[0];
    const float* k    = (const float*)d_in[1];
    const float* v    = (const float*)d_in[2];
    const int*   mask = (const int*)d_in[3];
    const float* Wq   = (const float*)d_in[4];
    const float* Wk   = (const float*)d_in[5];
    const float* Wv   = (const float*)d_in[6];
    const float* Wo   = (const float*)d_in[7];
    float* out = (float*)d_out;

    char* ws = (char*)d_ws;
    const size_t SZH = (size_t)NB * SEQ * DM * 2;       // 8 MiB
    const size_t SZW = (size_t)DM * DM * 2;             // 2 MiB
    u16* qw   = (u16*)(ws);
    u16* kw   = (u16*)(ws + SZH);
    u16* vt   = (u16*)(ws + 2*SZH);
    u16* ctx  = (u16*)(ws + 3*SZH);
    u16* vb   = ctx;                                    // v bf16 (dead before ctx)
    u32* mbits= (u32*)(ws + 4*SZH);                     // 1 MiB
    u16* qb   = (u16*)(ws + 4*SZH + (1u<<20));
    u16* kb   = (u16*)(ws + 4*SZH + (1u<<20) + SZH);
    u16* Wqb  = (u16*)(ws + 4*SZH + (1u<<20) + 2*SZH);
    u16* Wkb  = (u16*)((char*)Wqb + SZW);
    u16* Wvb  = (u16*)((char*)Wqb + 2*SZW);
    u16* Wob  = (u16*)((char*)Wqb + 3*SZW);

    const float CSC = 0.18033688011112042f;             // 0.125 * log2(e)

    CvtArgs ca;
    ca.s[0]=q;  ca.d[0]=qb;  ca.scale[0]=1.f;
    ca.s[1]=k;  ca.d[1]=kb;  ca.scale[1]=1.f;
    ca.s[2]=v;  ca.d[2]=vb;  ca.scale[2]=1.f;
    ca.s[3]=Wq; ca.d[3]=Wqb; ca.scale[3]=CSC;
    ca.s[4]=Wk; ca.d[4]=Wkb; ca.scale[4]=1.f;
    ca.s[5]=Wv; ca.d[5]=Wvb; ca.scale[5]=1.f;
    ca.s[6]=Wo; ca.d[6]=Wob; ca.scale[6]=1.f;
    int st[8] = {0, 2048, 4096, 6144, 6656, 7168, 7680, 8192};
    for (int i = 0; i < 8; ++i) ca.start[i] = st[i];
    cvt_kernel<<<dim3(8192), dim3(256), 0, stream>>>(ca);

    maskpack_kernel<<<dim3(NB*SEQ*SEQ/256), dim3(256), 0, stream>>>(mask, mbits);

    QKVArgs ga;
    ga.A[0]=qb;  ga.B[0]=Wqb; ga.Y[0]=qw;
    ga.A[1]=kb;  ga.B[1]=Wkb; ga.Y[1]=kw;
    ga.A[2]=Wvb; ga.B[2]=vb;  ga.Y[2]=vt;
    gemm_qkv<<<dim3(32, 8, 3), dim3(256), 0, stream>>>(ga);

    attn_kernel<<<dim3(SEQ/128, NB*NH), dim3(256), 0, stream>>>(qw, kw, vt, mbits, ctx);

    gemm_out<<<dim3(64, 8), dim3(256), 0, stream>>>(ctx, Wob, out);
}

// Round 5
// 276.333 us; speedup vs baseline: 1.0742x; 1.0742x over previous
//
#include <hip/hip_runtime.h>
#include <hip/hip_bf16.h>
#include <stdint.h>
#include <string.h>

// B=2, S=2048, D_MODEL=1024, H=16, Dh=64
#define SEQ   2048
#define DM    1024
#define NH    16
#define NB    2

typedef __attribute__((ext_vector_type(8))) short bf16x8;
typedef __attribute__((ext_vector_type(4))) float f32x4;
typedef unsigned short u16;
typedef unsigned int   u32;

__device__ __forceinline__ u16 f2bf(float f) {
    u32 u = __float_as_uint(f);
    u += 0x7FFF + ((u >> 16) & 1);   // RNE
    return (u16)(u >> 16);
}
__device__ __forceinline__ u32 pk2bf(float a, float b) {
    __hip_bfloat162 p = __float22bfloat162_rn(make_float2(a, b));
    u32 u; memcpy(&u, &p, 4); return u;
}
__device__ __forceinline__ float fexp2(float x) {
#if __has_builtin(__builtin_amdgcn_exp2f)
    return __builtin_amdgcn_exp2f(x);
#else
    return exp2f(x);
#endif
}
// async global->LDS, 16B/lane; LDS dest = wave-uniform base + lane*16
__device__ __forceinline__ void gl_lds16(const void* g, void* l) {
    __builtin_amdgcn_global_load_lds(
        (const __attribute__((address_space(1))) u32*)g,
        (__attribute__((address_space(3))) u32*)l, 16, 0, 0);
}
// Raw barrier WITHOUT vmcnt(0) drain: wait until only N newest VMEM ops
// remain in flight, then s_barrier. "memory" clobber pins ordering.
__device__ __forceinline__ void wbar_vm3() { asm volatile("s_waitcnt vmcnt(3)\ns_barrier" ::: "memory"); }
__device__ __forceinline__ void wbar_vm4() { asm volatile("s_waitcnt vmcnt(4)\ns_barrier" ::: "memory"); }
__device__ __forceinline__ void wbar_vm6() { asm volatile("s_waitcnt vmcnt(6)\ns_barrier" ::: "memory"); }
__device__ __forceinline__ void vm_drain() { asm volatile("s_waitcnt vmcnt(0)" ::: "memory"); }

// ---------------------------------------------------------------------------
// fp32 -> bf16 bulk convert; Wq pre-scaled by 0.125*log2(e) (exp2 domain).
// ---------------------------------------------------------------------------
struct CvtArgs {
    const float* s[7];
    u16* d[7];
    float scale[7];
    int start[8];
};
__global__ __launch_bounds__(256) void cvt_kernel(CvtArgs a) {
    int bid = blockIdx.x;
    int seg = 0;
#pragma unroll
    for (int i = 1; i < 7; ++i) if (bid >= a.start[i]) seg = i;
    float sc = a.scale[seg];
    size_t base = (size_t)(bid - a.start[seg]) * 2048 + threadIdx.x * 8;
    const float4* s4 = (const float4*)(a.s[seg] + base);
    float4 x = s4[0], y = s4[1];
    u32 r[4];
    r[0] = pk2bf(x.x*sc, x.y*sc); r[1] = pk2bf(x.z*sc, x.w*sc);
    r[2] = pk2bf(y.x*sc, y.y*sc); r[3] = pk2bf(y.z*sc, y.w*sc);
    *(uint4*)(a.d[seg] + base) = *(uint4*)r;
}

// ---------------------------------------------------------------------------
// mask -> bits; word = bits[(b*2048+m)*64 + n/32]
// ---------------------------------------------------------------------------
__global__ void maskpack_kernel(const int* __restrict__ mask,
                                unsigned int* __restrict__ bits) {
    int gid = blockIdx.x * 256 + threadIdx.x;
    int m = mask[gid];
    unsigned long long bal = __ballot(m != 0);
    int lane = threadIdx.x & 63;
    if (lane == 0)       bits[gid >> 5] = (u32)(bal & 0xFFFFFFFFull);
    else if (lane == 32) bits[gid >> 5] = (u32)(bal >> 32);
}

// ---------------------------------------------------------------------------
// bf16 GEMM: Y[r][c] = sum_k A[r][k]*B[c][k], K=1024, BK=32.
// Triple-buffered LDS, prefetch distance 2, raw-barrier pipeline (no vmcnt(0)
// drains inside the loop). XOR swizzle (4 chunks/row) for conflict-free b128.
// RT=4: 128x128 tile; RT=2: 64x128. 256 threads, waves 2x2.
// mode 0: bf16 (B,H,S,64); mode 1: bf16 (B,H,64,S); mode 2: fp32 row-major.
// ---------------------------------------------------------------------------
template<int RT>
__device__ __forceinline__ void gemm_body(const u16* __restrict__ A,
                                          const u16* __restrict__ Bm,
                                          void* __restrict__ Y,
                                          int rtile, int ctile, int mode,
                                          u16* sA, u16* sB) {
    constexpr int ABUF = RT * 32 * 32;          // u16 per A buffer
    constexpr int BBUF = 128 * 32;
    const int tid  = threadIdx.x;
    const int wv   = tid >> 6, lane = tid & 63;
    const int quad = lane >> 4, ln = lane & 15;
    const int wr   = wv >> 1,  wc  = wv & 1;

    const int lr4 = lane >> 2;                          // row in 16-row shot
    const int lcc = ((lane & 3) ^ ((lane >> 3) & 3)) * 8;  // swizzled src col

    const u16* gA[RT/2]; u16* lA[RT/2];
#pragma unroll
    for (int s = 0; s < RT/2; ++s) {
        int seg = wv * (RT/2) + s;
        gA[s] = A + (size_t)(rtile * (RT*32) + seg*16 + lr4) * 1024 + lcc;
        lA[s] = sA + seg * 512;
    }
    const u16* gB[2]; u16* lB[2];
#pragma unroll
    for (int s = 0; s < 2; ++s) {
        int seg = wv * 2 + s;
        gB[s] = Bm + (size_t)(ctile * 128 + seg*16 + lr4) * 1024 + lcc;
        lB[s] = sB + seg * 512;
    }

    f32x4 acc[RT][4];
#pragma unroll
    for (int i = 0; i < RT; ++i)
#pragma unroll
        for (int j = 0; j < 4; ++j) acc[i][j] = (f32x4){0.f,0.f,0.f,0.f};

    const int c0 = (quad ^ ((ln >> 1) & 3)) * 8;

    // prologue: stage kt=0 -> buf0, kt=1 -> buf1
#pragma unroll
    for (int s = 0; s < RT/2; ++s) gl_lds16(gA[s], lA[s]);
#pragma unroll
    for (int s = 0; s < 2; ++s)    gl_lds16(gB[s], lB[s]);
#pragma unroll
    for (int s = 0; s < RT/2; ++s) gl_lds16(gA[s] + 32, lA[s] + ABUF);
#pragma unroll
    for (int s = 0; s < 2; ++s)    gl_lds16(gB[s] + 32, lB[s] + BBUF);

    int bc = 0, bp = 2;
    for (int kt = 0; kt < 32; ++kt) {
        if (RT == 4) wbar_vm4(); else wbar_vm3();   // drain kt's loads only
        int pk = (kt + 2) & 31;                     // wrap keeps waitcnt uniform
#pragma unroll
        for (int s = 0; s < RT/2; ++s) gl_lds16(gA[s] + pk*32, lA[s] + bp*ABUF);
#pragma unroll
        for (int s = 0; s < 2; ++s)    gl_lds16(gB[s] + pk*32, lB[s] + bp*BBUF);

        const u16* sAb = sA + bc * ABUF;
        const u16* sBb = sB + bc * BBUF;
        bf16x8 af[RT], bfr[4];
#pragma unroll
        for (int rt = 0; rt < RT; ++rt)
            af[rt] = *(const bf16x8*)(sAb + (wr*(RT*16) + rt*16 + ln) * 32 + c0);
#pragma unroll
        for (int ct = 0; ct < 4; ++ct)
            bfr[ct] = *(const bf16x8*)(sBb + (wc*64 + ct*16 + ln) * 32 + c0);
#pragma unroll
        for (int rt = 0; rt < RT; ++rt)
#pragma unroll
            for (int ct = 0; ct < 4; ++ct)
                acc[rt][ct] = __builtin_amdgcn_mfma_f32_16x16x32_bf16(
                    af[rt], bfr[ct], acc[rt][ct], 0, 0, 0);

        bc = (bc == 2) ? 0 : bc + 1;
        bp = (bp == 2) ? 0 : bp + 1;
    }
    vm_drain();   // in-flight gl_lds must not land after LDS is reallocated

#pragma unroll
    for (int rt = 0; rt < RT; ++rt) {
#pragma unroll
        for (int ct = 0; ct < 4; ++ct) {
#pragma unroll
            for (int i = 0; i < 4; ++i) {
                int R = rtile*(RT*32) + wr*(RT*16) + rt*16 + quad*4 + i;
                int C = ctile*128 + wc*64 + ct*16 + ln;
                float val = acc[rt][ct][i];
                if (mode == 0) {
                    int b = R >> 11, s = R & 2047, h = C >> 6, d = C & 63;
                    ((u16*)Y)[((size_t)((b*NH + h) * SEQ + s) << 6) + d] = f2bf(val);
                } else if (mode == 1) {
                    int h = R >> 6, d = R & 63, b = C >> 11, n = C & 2047;
                    ((u16*)Y)[((size_t)((b*NH + h) * 64 + d) << 11) + n] = f2bf(val);
                } else {
                    ((float*)Y)[(size_t)R * 1024 + C] = val;
                }
            }
        }
    }
}

struct QKVArgs { const u16* A[3]; const u16* B[3]; u16* Y[3]; };

__global__ __launch_bounds__(256) void gemm_qkv(QKVArgs g) {
    __shared__ u16 sA[3 * 128 * 32];
    __shared__ u16 sB[3 * 128 * 32];
    int z = blockIdx.z;
    if (z == 2)
        gemm_body<4>(g.A[2], g.B[2], g.Y[2], blockIdx.y, blockIdx.x, 1, sA, sB);
    else
        gemm_body<4>(g.A[z], g.B[z], g.Y[z], blockIdx.x, blockIdx.y, 0, sA, sB);
}

__global__ __launch_bounds__(256) void gemm_out(const u16* __restrict__ A,
                                                const u16* __restrict__ Bm,
                                                float* __restrict__ Y) {
    __shared__ u16 sA[3 * 64 * 32];
    __shared__ u16 sB[3 * 128 * 32];
    gemm_body<2>(A, Bm, Y, blockIdx.x, blockIdx.y, 2, sA, sB);
}

// ---------------------------------------------------------------------------
// Flash attention v3: S^T orientation + raw-barrier triple-buffer pipeline.
// QK computed as mfma(Kfrag, Qfrag) -> lane holds fixed m=ln, n=quad*4+i:
// P written with packed ds_write_b64 (4/mt), mask rows are ln-indexed.
// K/V prefetch distance 2 (3 buffers), mask uint2 prefetch distance 2.
// One raw s_barrier per iter, s_waitcnt vmcnt(6) (leaves newest iter's loads).
// ---------------------------------------------------------------------------
__global__ __launch_bounds__(256) void attn_kernel(
    const u16* __restrict__ qw,
    const u16* __restrict__ kw,
    const u16* __restrict__ vt,
    const u32* __restrict__ mbits,
    u16* __restrict__ ctx) {

    constexpr int RSD = 36;                 // sP row stride in dwords (72 u16)
    __shared__ u16 sK[3 * 4096];
    __shared__ u16 sV[3 * 4096];
    __shared__ u32 sPd[4 * 32 * RSD];       // 18 KB

    const int mtile = blockIdx.x;           // 0..15 (128 m-rows each)
    const int bh    = blockIdx.y;           // 0..31
    const int b     = bh >> 4;
    const int tid   = threadIdx.x;
    const int wv    = tid >> 6, lane = tid & 63;
    const int quad  = lane >> 4, ln = lane & 15;
    const int m0    = mtile * 128;

    const size_t hbase = (size_t)bh * SEQ * 64;

    // Q fragments (B operand of S^T): rows m = m0 + wv*32 + mt*16 + ln
    bf16x8 qf[2][2];
#pragma unroll
    for (int mt = 0; mt < 2; ++mt) {
        const u16* qp = qw + hbase + (size_t)(m0 + wv*32 + mt*16 + ln) * 64 + quad*8;
        qf[mt][0] = *(const bf16x8*)(qp);
        qf[mt][1] = *(const bf16x8*)(qp + 32);
    }

    f32x4 o[2][4], lsum[2];
#pragma unroll
    for (int mt = 0; mt < 2; ++mt) {
        lsum[mt] = (f32x4){0.f,0.f,0.f,0.f};
#pragma unroll
        for (int j = 0; j < 4; ++j) o[mt][j] = (f32x4){0.f,0.f,0.f,0.f};
    }

    bf16x8 ones;
#pragma unroll
    for (int i = 0; i < 8; ++i) ones[i] = (short)0x3F80;   // bf16 1.0

    const u32* mrow[2];
#pragma unroll
    for (int mt = 0; mt < 2; ++mt)
        mrow[mt] = mbits + (size_t)(b*SEQ + m0 + wv*32 + mt*16 + ln) * 64;

    // K/V staging: 2 shots each per wave; XOR-swizzled source chunk
    const int lr = lane >> 3;
    const int lc = (lane & 7) ^ lr;
    const u16* gK[2]; const u16* gV[2];
    u16 *lK[2], *lV[2];
#pragma unroll
    for (int s = 0; s < 2; ++s) {
        int seg = s * 4 + wv;
        gK[s] = kw + hbase + (size_t)(seg*8 + lr) * 64 + lc*8;
        gV[s] = vt + hbase + (size_t)(seg*8 + lr) * SEQ + lc*8;
        lK[s] = sK + seg * 512;
        lV[s] = sV + seg * 512;
    }

    const int c0 = (quad ^ (ln & 7)) * 8;
    u32* sPw = sPd + wv * 32 * RSD;
    const u16* sP16 = (const u16*)sPd;

    // prologue: tiles 0 and 1 -> bufs 0, 1 (order: KV then mask, per tile)
#pragma unroll
    for (int s = 0; s < 2; ++s) { gl_lds16(gK[s], lK[s]); gl_lds16(gV[s], lV[s]); }
    uint2 wwA[2], wwB[2], wwC[2];
#pragma unroll
    for (int mt = 0; mt < 2; ++mt) wwA[mt] = *(const uint2*)(mrow[mt]);
#pragma unroll
    for (int s = 0; s < 2; ++s) {
        gl_lds16(gK[s] + 4096, lK[s] + 4096);
        gl_lds16(gV[s] + 64,   lV[s] + 4096);
    }
#pragma unroll
    for (int mt = 0; mt < 2; ++mt) wwB[mt] = *(const uint2*)(mrow[mt] + 2);

    int bc = 0, bp = 2;
    for (int nt = 0; nt < SEQ / 64; ++nt) {
        wbar_vm6();                          // drain tile nt's 6 loads only
        int pidx = (nt + 2) & 31;            // wrap keeps waitcnt uniform
#pragma unroll
        for (int s = 0; s < 2; ++s) {
            gl_lds16(gK[s] + (size_t)pidx * 4096, lK[s] + bp*4096);
            gl_lds16(gV[s] + pidx * 64,           lV[s] + bp*4096);
        }
#pragma unroll
        for (int mt = 0; mt < 2; ++mt)
            wwC[mt] = *(const uint2*)(mrow[mt] + pidx*2);

        const u16* sKb = sK + bc * 4096;
        const u16* sVb = sV + bc * 4096;

        // S^T = K Q^T: D[row=quad*4+i -> n][col=ln -> m]
        f32x4 s4[2][4];
#pragma unroll
        for (int ct = 0; ct < 4; ++ct) {
            const u16* kp = sKb + (ct*16 + ln) * 64;
            bf16x8 k0 = *(const bf16x8*)(kp + c0);
            bf16x8 k1 = *(const bf16x8*)(kp + (c0 ^ 32));
#pragma unroll
            for (int mt = 0; mt < 2; ++mt) {
                f32x4 z = (f32x4){0.f, 0.f, 0.f, 0.f};
                z = __builtin_amdgcn_mfma_f32_16x16x32_bf16(k0, qf[mt][0], z, 0, 0, 0);
                z = __builtin_amdgcn_mfma_f32_16x16x32_bf16(k1, qf[mt][1], z, 0, 0, 0);
                s4[mt][ct] = z;
            }
        }

        // p = exp2(masked ? -1e9 : s); packed b64 writes into wave-private sP
#pragma unroll
        for (int mt = 0; mt < 2; ++mt) {
            u32 w0 = wwA[mt].x >> (quad * 4);
            u32 w1 = wwA[mt].y >> (quad * 4);
#pragma unroll
            for (int ct = 0; ct < 4; ++ct) {
                u32 wsel = (ct & 2) ? w1 : w0;
                float p[4];
#pragma unroll
                for (int i = 0; i < 4; ++i) {
                    bool msk = (wsel >> ((ct & 1) * 16 + i)) & 1u;
                    p[i] = fexp2(msk ? -1e9f : s4[mt][ct][i]);
                }
                uint2 pk;
                pk.x = pk2bf(p[0], p[1]);
                pk.y = pk2bf(p[2], p[3]);
                *(uint2*)(sPw + (mt*16 + ln) * RSD + ct*8 + quad*2) = pk;
            }
        }
        // no barrier: sP region is wave-private (in-wave lgkm ordering)

        // O += P V ; lsum += P * ones
#pragma unroll
        for (int mt = 0; mt < 2; ++mt) {
            const u16* pp = sP16 + (wv*32 + mt*16 + ln) * 72;
            bf16x8 pf0 = *(const bf16x8*)(pp + quad*8);
            bf16x8 pf1 = *(const bf16x8*)(pp + 32 + quad*8);
            lsum[mt] = __builtin_amdgcn_mfma_f32_16x16x32_bf16(pf0, ones, lsum[mt], 0, 0, 0);
            lsum[mt] = __builtin_amdgcn_mfma_f32_16x16x32_bf16(pf1, ones, lsum[mt], 0, 0, 0);
#pragma unroll
            for (int ct = 0; ct < 4; ++ct) {
                const u16* vp = sVb + (ct*16 + ln) * 64;
                bf16x8 v0 = *(const bf16x8*)(vp + c0);
                bf16x8 v1 = *(const bf16x8*)(vp + (c0 ^ 32));
                o[mt][ct] = __builtin_amdgcn_mfma_f32_16x16x32_bf16(pf0, v0, o[mt][ct], 0, 0, 0);
                o[mt][ct] = __builtin_amdgcn_mfma_f32_16x16x32_bf16(pf1, v1, o[mt][ct], 0, 0, 0);
            }
        }

        wwA[0] = wwB[0]; wwA[1] = wwB[1];
        wwB[0] = wwC[0]; wwB[1] = wwC[1];
        bc = (bc == 2) ? 0 : bc + 1;
        bp = (bp == 2) ? 0 : bp + 1;
    }
    vm_drain();   // in-flight gl_lds must not land after LDS is reallocated

#pragma unroll
    for (int mt = 0; mt < 2; ++mt)
#pragma unroll
        for (int i = 0; i < 4; ++i) {
            float inv = 1.f / lsum[mt][i];
            int m = m0 + wv*32 + mt*16 + quad*4 + i;
            size_t base = ((size_t)(b * SEQ + m) << 10) + (bh & 15) * 64;
#pragma unroll
            for (int ct = 0; ct < 4; ++ct)
                ctx[base + ct*16 + ln] = f2bf(o[mt][ct][i] * inv);
        }
}

// ---------------------------------------------------------------------------
extern "C" void kernel_launch(void* const* d_in, const int* in_sizes, int n_in,
                              void* d_out, int out_size, void* d_ws, size_t ws_size,
                              hipStream_t stream) {
    const float* q    = (const float*)d_in[0];
    const float* k    = (const float*)d_in[1];
    const float* v    = (const float*)d_in[2];
    const int*   mask = (const int*)d_in[3];
    const float* Wq   = (const float*)d_in[4];
    const float* Wk   = (const float*)d_in[5];
    const float* Wv   = (const float*)d_in[6];
    const float* Wo   = (const float*)d_in[7];
    float* out = (float*)d_out;

    char* ws = (char*)d_ws;
    const size_t SZH = (size_t)NB * SEQ * DM * 2;       // 8 MiB
    const size_t SZW = (size_t)DM * DM * 2;             // 2 MiB
    u16* qw   = (u16*)(ws);
    u16* kw   = (u16*)(ws + SZH);
    u16* vt   = (u16*)(ws + 2*SZH);
    u16* ctx  = (u16*)(ws + 3*SZH);
    u16* vb   = ctx;                                    // v bf16 (dead before ctx)
    u32* mbits= (u32*)(ws + 4*SZH);                     // 1 MiB
    u16* qb   = (u16*)(ws + 4*SZH + (1u<<20));
    u16* kb   = (u16*)(ws + 4*SZH + (1u<<20) + SZH);
    u16* Wqb  = (u16*)(ws + 4*SZH + (1u<<20) + 2*SZH);
    u16* Wkb  = (u16*)((char*)Wqb + SZW);
    u16* Wvb  = (u16*)((char*)Wqb + 2*SZW);
    u16* Wob  = (u16*)((char*)Wqb + 3*SZW);

    const float CSC = 0.18033688011112042f;             // 0.125 * log2(e)

    CvtArgs ca;
    ca.s[0]=q;  ca.d[0]=qb;  ca.scale[0]=1.f;
    ca.s[1]=k;  ca.d[1]=kb;  ca.scale[1]=1.f;
    ca.s[2]=v;  ca.d[2]=vb;  ca.scale[2]=1.f;
    ca.s[3]=Wq; ca.d[3]=Wqb; ca.scale[3]=CSC;
    ca.s[4]=Wk; ca.d[4]=Wkb; ca.scale[4]=1.f;
    ca.s[5]=Wv; ca.d[5]=Wvb; ca.scale[5]=1.f;
    ca.s[6]=Wo; ca.d[6]=Wob; ca.scale[6]=1.f;
    int st[8] = {0, 2048, 4096, 6144, 6656, 7168, 7680, 8192};
    for (int i = 0; i < 8; ++i) ca.start[i] = st[i];
    cvt_kernel<<<dim3(8192), dim3(256), 0, stream>>>(ca);

    maskpack_kernel<<<dim3(NB*SEQ*SEQ/256), dim3(256), 0, stream>>>(mask, mbits);

    QKVArgs ga;
    ga.A[0]=qb;  ga.B[0]=Wqb; ga.Y[0]=qw;
    ga.A[1]=kb;  ga.B[1]=Wkb; ga.Y[1]=kw;
    ga.A[2]=Wvb; ga.B[2]=vb;  ga.Y[2]=vt;
    gemm_qkv<<<dim3(32, 8, 3), dim3(256), 0, stream>>>(ga);

    attn_kernel<<<dim3(SEQ/128, NB*NH), dim3(256), 0, stream>>>(qw, kw, vt, mbits, ctx);

    gemm_out<<<dim3(64, 8), dim3(256), 0, stream>>>(ctx, Wob, out);
}